// Round 3
// baseline (366.852 us; speedup 1.0000x reference)
//
#include <hip/hip_runtime.h>
#include <math.h>

#define BB 2
#define LL 1536
#define DD 768
#define HH 12
#define DKK 64
#define ZNEG -5.0e8f   // NEG/2: reference masks scores to -1e9, then z = scores/2

// ---------------------------------------------------------------------------
// Kernel 1: fused Q/K projection.  out[m,n] = sum_k X[m,k]*W[n,k] + bias[n]
// X: [3072, 768] row-major, W: [768, 768] row-major (we need X @ W^T -> both
// operands are K-contiguous). 64x64 tile, BK=16, 256 threads, 4x4 microtile.
// ---------------------------------------------------------------------------
__global__ __launch_bounds__(256) void proj_gemm(
    const float* __restrict__ Xq, const float* __restrict__ Xk,
    const float* __restrict__ Wq, const float* __restrict__ Wk,
    const float* __restrict__ bq, const float* __restrict__ bk,
    float* __restrict__ Qp, float* __restrict__ Kp)
{
    const float* X    = blockIdx.z ? Xk : Xq;
    const float* W    = blockIdx.z ? Wk : Wq;
    const float* bias = blockIdx.z ? bk : bq;
    float*       Out  = blockIdx.z ? Kp : Qp;

    __shared__ float As[16][68];   // [k][m], pad 68 -> rows 16B aligned, 2-way banks
    __shared__ float Bs[16][68];   // [k][n]

    const int m0 = blockIdx.y * 64;
    const int n0 = blockIdx.x * 64;
    const int tid = threadIdx.x;
    const int lr = tid >> 2;           // 0..63 : row within tile
    const int lk = (tid & 3) << 2;     // 0,4,8,12 : k start
    const int tm = tid >> 4;           // 0..15
    const int tn = tid & 15;           // 0..15

    const float* Arow = X + (size_t)(m0 + lr) * DD + lk;
    const float* Brow = W + (size_t)(n0 + lr) * DD + lk;

    float acc[4][4] = {};

    for (int k0 = 0; k0 < DD; k0 += 16) {
        float4 va = *reinterpret_cast<const float4*>(Arow + k0);
        float4 vb = *reinterpret_cast<const float4*>(Brow + k0);
        As[lk + 0][lr] = va.x; As[lk + 1][lr] = va.y;
        As[lk + 2][lr] = va.z; As[lk + 3][lr] = va.w;
        Bs[lk + 0][lr] = vb.x; Bs[lk + 1][lr] = vb.y;
        Bs[lk + 2][lr] = vb.z; Bs[lk + 3][lr] = vb.w;
        __syncthreads();
        #pragma unroll
        for (int kk = 0; kk < 16; ++kk) {
            float4 av = *reinterpret_cast<const float4*>(&As[kk][tm << 2]);
            float4 bv = *reinterpret_cast<const float4*>(&Bs[kk][tn << 2]);
            float a[4] = {av.x, av.y, av.z, av.w};
            float b[4] = {bv.x, bv.y, bv.z, bv.w};
            #pragma unroll
            for (int i = 0; i < 4; ++i)
                #pragma unroll
                for (int j = 0; j < 4; ++j)
                    acc[i][j] = fmaf(a[i], b[j], acc[i][j]);
        }
        __syncthreads();
    }

    #pragma unroll
    for (int i = 0; i < 4; ++i) {
        const int m = m0 + (tm << 2) + i;
        #pragma unroll
        for (int j = 0; j < 4; ++j) {
            const int n = n0 + (tn << 2) + j;
            Out[(size_t)m * DD + n] = acc[i][j] + bias[n];
        }
    }
}

// ---------------------------------------------------------------------------
// Kernel 2: scores z = (q . k) / (8 * 2), masked keys -> ZNEG.
// Per (b,h): GEMM M=N=1536, K=64 (single LDS stage). 64x64 tile.
// S layout: [B,H,Lq,Lk]
// ---------------------------------------------------------------------------
__global__ __launch_bounds__(256) void scores_gemm(
    const float* __restrict__ Qp, const float* __restrict__ Kp,
    const int* __restrict__ mask, float* __restrict__ S)
{
    const int bh = blockIdx.z;
    const int b  = bh / HH;
    const int h  = bh - b * HH;
    const int q0 = blockIdx.y * 64;
    const int n0 = blockIdx.x * 64;

    __shared__ float As[64][68];   // [k][q]
    __shared__ float Bs[64][68];   // [k][n]

    const int tid = threadIdx.x;
    const int lr = tid >> 2;           // 0..63 : row within tile
    const int lk = (tid & 3) << 4;     // 0,16,32,48 : k start (16 each)

    const float* Arow = Qp + (size_t)(b * LL + q0 + lr) * DD + h * DKK + lk;
    const float* Brow = Kp + (size_t)(b * LL + n0 + lr) * DD + h * DKK + lk;

    #pragma unroll
    for (int i = 0; i < 16; i += 4) {
        float4 va = *reinterpret_cast<const float4*>(Arow + i);
        As[lk + i + 0][lr] = va.x; As[lk + i + 1][lr] = va.y;
        As[lk + i + 2][lr] = va.z; As[lk + i + 3][lr] = va.w;
        float4 vb = *reinterpret_cast<const float4*>(Brow + i);
        Bs[lk + i + 0][lr] = vb.x; Bs[lk + i + 1][lr] = vb.y;
        Bs[lk + i + 2][lr] = vb.z; Bs[lk + i + 3][lr] = vb.w;
    }
    __syncthreads();

    const int tm = tid >> 4;
    const int tn = tid & 15;
    float acc[4][4] = {};
    #pragma unroll
    for (int kk = 0; kk < 64; ++kk) {
        float4 av = *reinterpret_cast<const float4*>(&As[kk][tm << 2]);
        float4 bv = *reinterpret_cast<const float4*>(&Bs[kk][tn << 2]);
        float a[4] = {av.x, av.y, av.z, av.w};
        float b4[4] = {bv.x, bv.y, bv.z, bv.w};
        #pragma unroll
        for (int i = 0; i < 4; ++i)
            #pragma unroll
            for (int j = 0; j < 4; ++j)
                acc[i][j] = fmaf(a[i], b4[j], acc[i][j]);
    }

    const int coln = n0 + (tn << 2);
    const int* mrow = mask + b * LL;
    int msk[4];
    #pragma unroll
    for (int j = 0; j < 4; ++j) msk[j] = mrow[coln + j];

    #pragma unroll
    for (int i = 0; i < 4; ++i) {
        const size_t base = ((size_t)bh * LL + (q0 + (tm << 2) + i)) * LL + coln;
        #pragma unroll
        for (int j = 0; j < 4; ++j) {
            const float v = acc[i][j] * 0.0625f;   // (qk/8)/2
            S[base + j] = msk[j] ? v : ZNEG;
        }
    }
}

// ---------------------------------------------------------------------------
// Kernel 3: entmax-1.5, wave-per-head version.
// One 256-thread block (4 waves) per (b,q). Wave w handles heads w, w+4, w+8.
// Lane l owns 24 contiguous columns [l*24, l*24+24) of the 1536-wide row.
// tau* is the unique root of f(tau) = sum max(z - tau, 0)^2 = 1 with
// tau* in [max-1, max]; 16 bisection steps -> |dtau| <= 7.6e-6 ->
// p error <= 2*dtau <= 1.6e-5 << 8.25e-4 threshold.
// All bisection reductions are intra-wave shuffle butterflies (no barriers);
// a single __syncthreads joins the 4 waves' head-partials at the end.
// ---------------------------------------------------------------------------
__device__ __forceinline__ float waveReduceSum(float v) {
    #pragma unroll
    for (int off = 32; off > 0; off >>= 1) v += __shfl_xor(v, off, 64);
    return v;
}
__device__ __forceinline__ float waveReduceMax(float v) {
    #pragma unroll
    for (int off = 32; off > 0; off >>= 1) v = fmaxf(v, __shfl_xor(v, off, 64));
    return v;
}

__global__ __launch_bounds__(256) void entmax_sum(
    const float* __restrict__ S, float* __restrict__ out)
{
    const int bq = blockIdx.x;          // b*LL + q
    const int b  = bq / LL;
    const int q  = bq - b * LL;
    const int tid = threadIdx.x;
    const int w  = tid >> 6;            // wave 0..3
    const int l  = tid & 63;            // lane 0..63

    __shared__ float buf[4][LL];        // per-wave head-partials, 24 KB

    float acc[24];
    #pragma unroll
    for (int i = 0; i < 24; ++i) acc[i] = 0.0f;

    #pragma unroll
    for (int hi = 0; hi < 3; ++hi) {
        const int h = w + (hi << 2);
        const float* row = S + ((size_t)(b * HH + h) * LL + q) * LL + l * 24;

        float z[24];
        #pragma unroll
        for (int i = 0; i < 24; i += 4) {
            float4 v = *reinterpret_cast<const float4*>(row + i);
            z[i] = v.x; z[i + 1] = v.y; z[i + 2] = v.z; z[i + 3] = v.w;
        }

        // ---- wave max ----
        float m = z[0];
        #pragma unroll
        for (int i = 1; i < 24; ++i) m = fmaxf(m, z[i]);
        m = waveReduceMax(m);

        #pragma unroll
        for (int i = 0; i < 24; ++i) z[i] -= m;

        // ---- bisection for tau in [-1, 0] ----
        float lo = -1.0f, hi_ = 0.0f;
        for (int it = 0; it < 16; ++it) {
            const float tau = 0.5f * (lo + hi_);
            float s = 0.0f;
            #pragma unroll
            for (int i = 0; i < 24; ++i) {
                const float t = fmaxf(z[i] - tau, 0.0f);
                s = fmaf(t, t, s);
            }
            s = waveReduceSum(s);
            if (s >= 1.0f) lo = tau; else hi_ = tau;
        }
        const float tau = 0.5f * (lo + hi_);

        #pragma unroll
        for (int i = 0; i < 24; ++i) {
            const float t = fmaxf(z[i] - tau, 0.0f);
            acc[i] = fmaf(t, t, acc[i]);
        }
    }

    // ---- join the 4 waves' head-partials ----
    #pragma unroll
    for (int i = 0; i < 24; ++i) buf[w][l * 24 + i] = acc[i];
    __syncthreads();

    float* orow = out + (size_t)bq * LL;
    #pragma unroll
    for (int i = 0; i < 6; ++i) {
        const int c = tid + (i << 8);
        orow[c] = (buf[0][c] + buf[1][c] + buf[2][c] + buf[3][c]) * (1.0f / 12.0f);
    }
}

// ---------------------------------------------------------------------------
extern "C" void kernel_launch(void* const* d_in, const int* in_sizes, int n_in,
                              void* d_out, int out_size, void* d_ws, size_t ws_size,
                              hipStream_t stream) {
    (void)in_sizes; (void)n_in; (void)out_size; (void)ws_size;
    const float* query = (const float*)d_in[0];
    const float* key   = (const float*)d_in[1];
    const int*   mask  = (const int*)d_in[2];
    const float* wq_w  = (const float*)d_in[3];
    const float* wq_b  = (const float*)d_in[4];
    const float* wk_w  = (const float*)d_in[5];
    const float* wk_b  = (const float*)d_in[6];
    float* out = (float*)d_out;

    float* Qp = (float*)d_ws;                       // [B,L,D]  9.4 MB
    float* Kp = Qp + (size_t)BB * LL * DD;          // [B,L,D]  9.4 MB
    float* S  = Kp + (size_t)BB * LL * DD;          // [B,H,L,L] 226.5 MB

    // K1: projections (z dim: 0 = Q, 1 = K)
    proj_gemm<<<dim3(DD / 64, (BB * LL) / 64, 2), 256, 0, stream>>>(
        query, key, wq_w, wk_w, wq_b, wk_b, Qp, Kp);

    // K2: masked, pre-scaled scores
    scores_gemm<<<dim3(LL / 64, LL / 64, BB * HH), 256, 0, stream>>>(
        Qp, Kp, mask, S);

    // K3: entmax + head average
    entmax_sum<<<BB * LL, 256, 0, stream>>>(S, out);
}

// Round 4
// 253.732 us; speedup vs baseline: 1.4458x; 1.4458x over previous
//
#include <hip/hip_runtime.h>
#include <math.h>

#define BB 2
#define LL 1536
#define DD 768
#define HH 12
#define DKK 64
#define ZNEG -5.0e8f   // NEG/2: reference masks scores to -1e9, then z = scores/2

typedef __attribute__((ext_vector_type(8))) short bf16x8;           // 8 bf16 (4 VGPRs)
typedef __attribute__((ext_vector_type(8))) unsigned short u16x8;
typedef __attribute__((ext_vector_type(4))) float f32x4;

__device__ __forceinline__ unsigned short f32_to_bf16_rn(float x) {
    unsigned int u = __float_as_uint(x);
    u += 0x7fffu + ((u >> 16) & 1u);          // round-to-nearest-even
    return (unsigned short)(u >> 16);
}
__device__ __forceinline__ float bf16u_to_f32(unsigned short h) {
    return __uint_as_float(((unsigned int)h) << 16);
}

// Split 8 consecutive f32 into bf16 hi/lo halves; store 16 B of each to LDS.
// x = hi + lo with |lo| <= 2^-9 |x| (exact difference), lo re-rounded to bf16
// adds <= 2^-18 |x| error -> f32-grade precision after 3-term MFMA.
__device__ __forceinline__ void split8(const float* __restrict__ gsrc,
                                       unsigned short* __restrict__ hdst,
                                       unsigned short* __restrict__ ldst) {
    float4 v0 = *reinterpret_cast<const float4*>(gsrc);
    float4 v1 = *reinterpret_cast<const float4*>(gsrc + 4);
    float f[8] = {v0.x, v0.y, v0.z, v0.w, v1.x, v1.y, v1.z, v1.w};
    u16x8 hi, lo;
    #pragma unroll
    for (int i = 0; i < 8; ++i) {
        unsigned short h = f32_to_bf16_rn(f[i]);
        float r = f[i] - bf16u_to_f32(h);
        hi[i] = h;
        lo[i] = f32_to_bf16_rn(r);
    }
    *reinterpret_cast<u16x8*>(hdst) = hi;
    *reinterpret_cast<u16x8*>(ldst) = lo;
}

// ---------------------------------------------------------------------------
// Kernel 1: fused Q/K projection via split-bf16 MFMA.
// out[m,n] = sum_k X[m,k]*W[n,k] + bias[n];  M=3072, N=768, K=768.
// Block tile 128x64, BK=32, 4 waves each computing 64x32 (4 m-frags x 2 n-frags
// of 16x16x32). LDS is fragment-major: frag f, lane l -> 16B at (f*64+l)*16
// => conflict-free ds_read_b128 / ds_write_b128.
// ---------------------------------------------------------------------------
__global__ __launch_bounds__(256) void proj_mfma(
    const float* __restrict__ Xq, const float* __restrict__ Xk,
    const float* __restrict__ Wq, const float* __restrict__ Wk,
    const float* __restrict__ bq, const float* __restrict__ bk,
    float* __restrict__ Qp, float* __restrict__ Kp)
{
    const float* X    = blockIdx.z ? Xk : Xq;
    const float* W    = blockIdx.z ? Wk : Wq;
    const float* bias = blockIdx.z ? bk : bq;
    float*       Out  = blockIdx.z ? Kp : Qp;

    __shared__ alignas(16) unsigned short Ah[8 * 64 * 8];  // 8 KB
    __shared__ alignas(16) unsigned short Al[8 * 64 * 8];  // 8 KB
    __shared__ alignas(16) unsigned short Bh[4 * 64 * 8];  // 4 KB
    __shared__ alignas(16) unsigned short Bl[4 * 64 * 8];  // 4 KB

    const int tid  = threadIdx.x;
    const int lane = tid & 63;
    const int w    = tid >> 6;
    const int wm   = w & 1;          // 2 m-halves of 64 rows
    const int wn   = w >> 1;         // 2 n-halves of 32 cols
    const int m0   = blockIdx.y * 128;
    const int n0   = blockIdx.x * 64;

    f32x4 acc[4][2] = {};

    for (int k0 = 0; k0 < DD; k0 += 32) {
        // ---- stage A: 512 8-float chunks (m 0..127, g 0..3) ----
        #pragma unroll
        for (int i = 0; i < 2; ++i) {
            const int c = tid + (i << 8);
            const int m = c >> 2, g = c & 3;
            const int slot = ((m >> 4) * 64 + (m & 15) + (g << 4)) * 8;
            split8(X + (size_t)(m0 + m) * DD + k0 + g * 8, Ah + slot, Al + slot);
        }
        // ---- stage B: 256 chunks (n 0..63, g 0..3) ----
        {
            const int n = tid >> 2, g = tid & 3;
            const int slot = ((n >> 4) * 64 + (n & 15) + (g << 4)) * 8;
            split8(W + (size_t)(n0 + n) * DD + k0 + g * 8, Bh + slot, Bl + slot);
        }
        __syncthreads();

        bf16x8 aH[4], aL[4], bH[2], bL[2];
        #pragma unroll
        for (int fm = 0; fm < 4; ++fm) {
            const int f = wm * 4 + fm;
            aH[fm] = *reinterpret_cast<const bf16x8*>(Ah + (f * 64 + lane) * 8);
            aL[fm] = *reinterpret_cast<const bf16x8*>(Al + (f * 64 + lane) * 8);
        }
        #pragma unroll
        for (int fn = 0; fn < 2; ++fn) {
            const int f = wn * 2 + fn;
            bH[fn] = *reinterpret_cast<const bf16x8*>(Bh + (f * 64 + lane) * 8);
            bL[fn] = *reinterpret_cast<const bf16x8*>(Bl + (f * 64 + lane) * 8);
        }
        #pragma unroll
        for (int fm = 0; fm < 4; ++fm)
            #pragma unroll
            for (int fn = 0; fn < 2; ++fn) {
                acc[fm][fn] = __builtin_amdgcn_mfma_f32_16x16x32_bf16(aH[fm], bH[fn], acc[fm][fn], 0, 0, 0);
                acc[fm][fn] = __builtin_amdgcn_mfma_f32_16x16x32_bf16(aH[fm], bL[fn], acc[fm][fn], 0, 0, 0);
                acc[fm][fn] = __builtin_amdgcn_mfma_f32_16x16x32_bf16(aL[fm], bH[fn], acc[fm][fn], 0, 0, 0);
            }
        __syncthreads();
    }

    // ---- epilogue: C/D layout col=lane&15, row=(lane>>4)*4+reg [m89] ----
    const int r0 = (lane >> 4) << 2;
    const int cl = lane & 15;
    #pragma unroll
    for (int fn = 0; fn < 2; ++fn) {
        const int col = n0 + wn * 32 + fn * 16 + cl;
        const float bv = bias[col];
        #pragma unroll
        for (int fm = 0; fm < 4; ++fm) {
            const int row = m0 + wm * 64 + fm * 16 + r0;
            #pragma unroll
            for (int r = 0; r < 4; ++r)
                Out[(size_t)(row + r) * DD + col] = acc[fm][fn][r] + bv;
        }
    }
}

// ---------------------------------------------------------------------------
// Kernel 2: scores z = (q.k)/16, masked keys -> ZNEG, via split-bf16 MFMA.
// Per (b,h): M=N=1536, K=64 (2 k-chunks of 32, staged once). Tile 128x64.
// ---------------------------------------------------------------------------
__global__ __launch_bounds__(256) void scores_mfma(
    const float* __restrict__ Qp, const float* __restrict__ Kp,
    const int* __restrict__ mask, float* __restrict__ S)
{
    const int bh = blockIdx.z;
    const int b  = bh / HH;
    const int h  = bh - b * HH;
    const int q0 = blockIdx.y * 128;
    const int n0 = blockIdx.x * 64;

    __shared__ alignas(16) unsigned short Ah[8 * 2 * 64 * 8];  // 16 KB
    __shared__ alignas(16) unsigned short Al[8 * 2 * 64 * 8];  // 16 KB
    __shared__ alignas(16) unsigned short Bh[4 * 2 * 64 * 8];  //  8 KB
    __shared__ alignas(16) unsigned short Bl[4 * 2 * 64 * 8];  //  8 KB

    const int tid  = threadIdx.x;
    const int lane = tid & 63;
    const int w    = tid >> 6;
    const int wm   = w & 1;
    const int wn   = w >> 1;

    // ---- stage A: 1024 chunks (m 0..127, c8 0..7) ----
    #pragma unroll
    for (int i = 0; i < 4; ++i) {
        const int c = tid + (i << 8);
        const int m = c >> 3, c8 = c & 7;
        const int qq = c8 >> 2, g = c8 & 3;
        const int slot = (((m >> 4) * 2 + qq) * 64 + (m & 15) + (g << 4)) * 8;
        split8(Qp + (size_t)(b * LL + q0 + m) * DD + h * DKK + c8 * 8, Ah + slot, Al + slot);
    }
    // ---- stage B: 512 chunks (n 0..63, c8 0..7) ----
    #pragma unroll
    for (int i = 0; i < 2; ++i) {
        const int c = tid + (i << 8);
        const int n = c >> 3, c8 = c & 7;
        const int qq = c8 >> 2, g = c8 & 3;
        const int slot = (((n >> 4) * 2 + qq) * 64 + (n & 15) + (g << 4)) * 8;
        split8(Kp + (size_t)(b * LL + n0 + n) * DD + h * DKK + c8 * 8, Bh + slot, Bl + slot);
    }
    __syncthreads();

    f32x4 acc[4][2] = {};
    #pragma unroll
    for (int qq = 0; qq < 2; ++qq) {
        bf16x8 aH[4], aL[4], bH[2], bL[2];
        #pragma unroll
        for (int fm = 0; fm < 4; ++fm) {
            const int f = (wm * 4 + fm) * 2 + qq;
            aH[fm] = *reinterpret_cast<const bf16x8*>(Ah + (f * 64 + lane) * 8);
            aL[fm] = *reinterpret_cast<const bf16x8*>(Al + (f * 64 + lane) * 8);
        }
        #pragma unroll
        for (int fn = 0; fn < 2; ++fn) {
            const int f = (wn * 2 + fn) * 2 + qq;
            bH[fn] = *reinterpret_cast<const bf16x8*>(Bh + (f * 64 + lane) * 8);
            bL[fn] = *reinterpret_cast<const bf16x8*>(Bl + (f * 64 + lane) * 8);
        }
        #pragma unroll
        for (int fm = 0; fm < 4; ++fm)
            #pragma unroll
            for (int fn = 0; fn < 2; ++fn) {
                acc[fm][fn] = __builtin_amdgcn_mfma_f32_16x16x32_bf16(aH[fm], bH[fn], acc[fm][fn], 0, 0, 0);
                acc[fm][fn] = __builtin_amdgcn_mfma_f32_16x16x32_bf16(aH[fm], bL[fn], acc[fm][fn], 0, 0, 0);
                acc[fm][fn] = __builtin_amdgcn_mfma_f32_16x16x32_bf16(aL[fm], bH[fn], acc[fm][fn], 0, 0, 0);
            }
    }

    // ---- epilogue: scale 1/16, mask, store f32 ----
    const int r0 = (lane >> 4) << 2;
    const int cl = lane & 15;
    #pragma unroll
    for (int fn = 0; fn < 2; ++fn) {
        const int col = n0 + wn * 32 + fn * 16 + cl;
        const int mk  = mask[b * LL + col];
        #pragma unroll
        for (int fm = 0; fm < 4; ++fm) {
            const int row = q0 + wm * 64 + fm * 16 + r0;
            const size_t base = ((size_t)bh * LL + row) * LL + col;
            #pragma unroll
            for (int r = 0; r < 4; ++r) {
                const float v = acc[fm][fn][r] * 0.0625f;   // (qk/8)/2
                S[base + (size_t)r * LL] = mk ? v : ZNEG;
            }
        }
    }
}

// ---------------------------------------------------------------------------
// Kernel 3: entmax-1.5, wave-per-head (unchanged from round 3, verified).
// ---------------------------------------------------------------------------
__device__ __forceinline__ float waveReduceSum(float v) {
    #pragma unroll
    for (int off = 32; off > 0; off >>= 1) v += __shfl_xor(v, off, 64);
    return v;
}
__device__ __forceinline__ float waveReduceMax(float v) {
    #pragma unroll
    for (int off = 32; off > 0; off >>= 1) v = fmaxf(v, __shfl_xor(v, off, 64));
    return v;
}

__global__ __launch_bounds__(256) void entmax_sum(
    const float* __restrict__ S, float* __restrict__ out)
{
    const int bq = blockIdx.x;          // b*LL + q
    const int b  = bq / LL;
    const int q  = bq - b * LL;
    const int tid = threadIdx.x;
    const int w  = tid >> 6;            // wave 0..3
    const int l  = tid & 63;            // lane 0..63

    __shared__ float buf[4][LL];        // per-wave head-partials, 24 KB

    float acc[24];
    #pragma unroll
    for (int i = 0; i < 24; ++i) acc[i] = 0.0f;

    #pragma unroll
    for (int hi = 0; hi < 3; ++hi) {
        const int h = w + (hi << 2);
        const float* row = S + ((size_t)(b * HH + h) * LL + q) * LL + l * 24;

        float z[24];
        #pragma unroll
        for (int i = 0; i < 24; i += 4) {
            float4 v = *reinterpret_cast<const float4*>(row + i);
            z[i] = v.x; z[i + 1] = v.y; z[i + 2] = v.z; z[i + 3] = v.w;
        }

        // ---- wave max ----
        float m = z[0];
        #pragma unroll
        for (int i = 1; i < 24; ++i) m = fmaxf(m, z[i]);
        m = waveReduceMax(m);

        #pragma unroll
        for (int i = 0; i < 24; ++i) z[i] -= m;

        // ---- bisection for tau in [-1, 0] ----
        float lo = -1.0f, hi_ = 0.0f;
        for (int it = 0; it < 16; ++it) {
            const float tau = 0.5f * (lo + hi_);
            float s = 0.0f;
            #pragma unroll
            for (int i = 0; i < 24; ++i) {
                const float t = fmaxf(z[i] - tau, 0.0f);
                s = fmaf(t, t, s);
            }
            s = waveReduceSum(s);
            if (s >= 1.0f) lo = tau; else hi_ = tau;
        }
        const float tau = 0.5f * (lo + hi_);

        #pragma unroll
        for (int i = 0; i < 24; ++i) {
            const float t = fmaxf(z[i] - tau, 0.0f);
            acc[i] = fmaf(t, t, acc[i]);
        }
    }

    // ---- join the 4 waves' head-partials ----
    #pragma unroll
    for (int i = 0; i < 24; ++i) buf[w][l * 24 + i] = acc[i];
    __syncthreads();

    float* orow = out + (size_t)bq * LL;
    #pragma unroll
    for (int i = 0; i < 6; ++i) {
        const int c = tid + (i << 8);
        orow[c] = (buf[0][c] + buf[1][c] + buf[2][c] + buf[3][c]) * (1.0f / 12.0f);
    }
}

// ---------------------------------------------------------------------------
extern "C" void kernel_launch(void* const* d_in, const int* in_sizes, int n_in,
                              void* d_out, int out_size, void* d_ws, size_t ws_size,
                              hipStream_t stream) {
    (void)in_sizes; (void)n_in; (void)out_size; (void)ws_size;
    const float* query = (const float*)d_in[0];
    const float* key   = (const float*)d_in[1];
    const int*   mask  = (const int*)d_in[2];
    const float* wq_w  = (const float*)d_in[3];
    const float* wq_b  = (const float*)d_in[4];
    const float* wk_w  = (const float*)d_in[5];
    const float* wk_b  = (const float*)d_in[6];
    float* out = (float*)d_out;

    float* Qp = (float*)d_ws;                       // [B,L,D]  9.4 MB
    float* Kp = Qp + (size_t)BB * LL * DD;          // [B,L,D]  9.4 MB
    float* S  = Kp + (size_t)BB * LL * DD;          // [B,H,L,L] 226.5 MB

    // K1: projections (z dim: 0 = Q, 1 = K)
    proj_mfma<<<dim3(DD / 64, (BB * LL) / 128, 2), 256, 0, stream>>>(
        query, key, wq_w, wk_w, wq_b, wk_b, Qp, Kp);

    // K2: masked, pre-scaled scores
    scores_mfma<<<dim3(LL / 64, LL / 128, BB * HH), 256, 0, stream>>>(
        Qp, Kp, mask, S);

    // K3: entmax + head average
    entmax_sum<<<BB * LL, 256, 0, stream>>>(S, out);
}